// Round 4
// baseline (15.883 us; speedup 1.0000x reference)
//
#include <hip/hip_runtime.h>
#include <hip/hip_bf16.h>

#define BB 8
#define VV 128
#define TT 512
#define ITILE 4      // i-rows per block
#define JTILE 2      // j-rows per wave-iteration
#define NWAVES 16    // 1024 threads per block -> 4 waves/SIMD

__global__ __launch_bounds__(1024)
void DiffGraphLearn_kernel(const float* __restrict__ x,
                           const float* __restrict__ w,
                           float* __restrict__ out) {
    const int blk  = blockIdx.x;           // b*32 + itile
    const int b    = blk >> 5;
    const int i0   = (blk & 31) * ITILE;
    const int tid  = threadIdx.x;
    const int lane = tid & 63;
    const int wave = tid >> 6;             // 0..15

    __shared__ float scores[ITILE][VV];

    const float* __restrict__ xb = x + (size_t)b * VV * TT;

    // Hoist w and the ITILE xi rows into registers (float4 index lane, lane+64).
    const float4* __restrict__ wf4 = (const float4*)w;
    const float4 w0 = wf4[lane];
    const float4 w1 = wf4[lane + 64];
    float4 xi0[ITILE], xi1[ITILE];
#pragma unroll
    for (int r = 0; r < ITILE; ++r) {
        const float4* xif = (const float4*)(xb + (size_t)(i0 + r) * TT);
        xi0[r] = xif[lane];
        xi1[r] = xif[lane + 64];
    }

    // j loop: wave handles j pairs {2*wave, 2*wave+1} + 32*s, s = 0..3.
    int j0 = 2 * wave;
    {
    const float4* p0 = (const float4*)(xb + (size_t)j0 * TT);
    const float4* p1 = (const float4*)(xb + (size_t)(j0 + 1) * TT);
    float4 a0 = p0[lane], c0 = p0[lane + 64];
    float4 a1 = p1[lane], c1 = p1[lane + 64];

    for (int s = 0; s < VV / (NWAVES * JTILE); ++s) {
        // Prefetch next iteration's two j-rows.
        float4 na0, nc0, na1, nc1;
        if (s < VV / (NWAVES * JTILE) - 1) {
            const float4* q0 = (const float4*)(xb + (size_t)(j0 + 32) * TT);
            const float4* q1 = (const float4*)(xb + (size_t)(j0 + 33) * TT);
            na0 = q0[lane]; nc0 = q0[lane + 64];
            na1 = q1[lane]; nc1 = q1[lane + 64];
        }

        float v[2 * ITILE];
#pragma unroll
        for (int r = 0; r < ITILE; ++r) {
            float s0 = 0.f, s1 = 0.f;
            s0 += fabsf(xi0[r].x - a0.x) * w0.x;
            s0 += fabsf(xi0[r].y - a0.y) * w0.y;
            s0 += fabsf(xi0[r].z - a0.z) * w0.z;
            s0 += fabsf(xi0[r].w - a0.w) * w0.w;
            s0 += fabsf(xi1[r].x - c0.x) * w1.x;
            s0 += fabsf(xi1[r].y - c0.y) * w1.y;
            s0 += fabsf(xi1[r].z - c0.z) * w1.z;
            s0 += fabsf(xi1[r].w - c0.w) * w1.w;
            s1 += fabsf(xi0[r].x - a1.x) * w0.x;
            s1 += fabsf(xi0[r].y - a1.y) * w0.y;
            s1 += fabsf(xi0[r].z - a1.z) * w0.z;
            s1 += fabsf(xi0[r].w - a1.w) * w0.w;
            s1 += fabsf(xi1[r].x - c1.x) * w1.x;
            s1 += fabsf(xi1[r].y - c1.y) * w1.y;
            s1 += fabsf(xi1[r].z - c1.z) * w1.z;
            s1 += fabsf(xi1[r].w - c1.w) * w1.w;
            v[2 * r]     = s0;
            v[2 * r + 1] = s1;
        }

        // Joint 8-value reduction: lane k (k = lane&7) ends with the full
        // 64-lane sum of v[k].  Routing steps have 4/2/1-wide ILP.
        float t0 = (lane & 1) ? v[1] : v[0], t0s = (lane & 1) ? v[0] : v[1];
        float t1 = (lane & 1) ? v[3] : v[2], t1s = (lane & 1) ? v[2] : v[3];
        float t2 = (lane & 1) ? v[5] : v[4], t2s = (lane & 1) ? v[4] : v[5];
        float t3 = (lane & 1) ? v[7] : v[6], t3s = (lane & 1) ? v[6] : v[7];
        t0 += __shfl_xor(t0s, 1, 64);
        t1 += __shfl_xor(t1s, 1, 64);
        t2 += __shfl_xor(t2s, 1, 64);
        t3 += __shfl_xor(t3s, 1, 64);
        float u0 = (lane & 2) ? t1 : t0, u0s = (lane & 2) ? t0 : t1;
        float u1 = (lane & 2) ? t3 : t2, u1s = (lane & 2) ? t2 : t3;
        u0 += __shfl_xor(u0s, 2, 64);
        u1 += __shfl_xor(u1s, 2, 64);
        float z = (lane & 4) ? u1 : u0, zs = (lane & 4) ? u0 : u1;
        z += __shfl_xor(zs, 4, 64);
        z += __shfl_xor(z, 8, 64);
        z += __shfl_xor(z, 16, 64);
        z += __shfl_xor(z, 32, 64);

        if (lane < 2 * ITILE)
            scores[lane >> 1][j0 + (lane & 1)] = fmaxf(z, 0.f);  // ReLU

        j0 += NWAVES * JTILE;
        a0 = na0; c0 = nc0; a1 = na1; c1 = nc1;
    }
    }
    __syncthreads();

    // Row softmax: waves 0..3 each handle one of the ITILE rows.
    if (wave < ITILE) {
        const float s0 = scores[wave][lane];
        const float s1 = scores[wave][lane + 64];
        float m = fmaxf(s0, s1);
#pragma unroll
        for (int off = 32; off >= 1; off >>= 1)
            m = fmaxf(m, __shfl_xor(m, off, 64));
        const float e0 = __expf(s0 - m);
        const float e1 = __expf(s1 - m);
        float sum = e0 + e1;
#pragma unroll
        for (int off = 32; off >= 1; off >>= 1)
            sum += __shfl_xor(sum, off, 64);
        const float inv = __frcp_rn(sum);
        float* __restrict__ o = out + ((size_t)b * VV + i0 + wave) * VV;
        o[lane]      = e0 * inv;
        o[lane + 64] = e1 * inv;
    }
}

extern "C" void kernel_launch(void* const* d_in, const int* in_sizes, int n_in,
                              void* d_out, int out_size, void* d_ws, size_t ws_size,
                              hipStream_t stream) {
    const float* x = (const float*)d_in[0];   // [8,128,512] f32
    const float* w = (const float*)d_in[1];   // [512] f32
    float* out = (float*)d_out;               // [8,128,128] f32

    dim3 grid(BB * (VV / ITILE));   // 256 blocks, one per CU
    dim3 block(NWAVES * 64);        // 1024 threads = 16 waves
    hipLaunchKernelGGL(DiffGraphLearn_kernel, grid, block, 0, stream, x, w, out);
}

// Round 5
// 13.085 us; speedup vs baseline: 1.2139x; 1.2139x over previous
//
#include <hip/hip_runtime.h>
#include <hip/hip_bf16.h>

#define BB 8
#define VV 128
#define TT 512
#define ITILE 4      // i-rows per block
#define JTILE 2      // j-rows per wave-iteration
#define NWAVES 16    // 1024 threads per block

__global__ __launch_bounds__(1024)
void DiffGraphLearn_kernel(const float* __restrict__ x,
                           const float* __restrict__ w,
                           float* __restrict__ out) {
    const int blk  = blockIdx.x;           // b*32 + itile
    const int b    = blk >> 5;
    const int i0   = (blk & 31) * ITILE;
    const int tid  = threadIdx.x;
    const int lane = tid & 63;
    const int wave = tid >> 6;             // 0..15

    __shared__ float xi_lds[ITILE * TT];          // 8 KB: the block's 4 i-rows
    __shared__ float sp[2 * ITILE][VV / 2][8];    // 16 KB: octet partial sums

    const float*  __restrict__ xb  = x + (size_t)b * VV * TT;
    const float4* __restrict__ xb4 = (const float4*)xb;

    // Stage the ITILE xi rows into LDS (512 float4, threads 0..511).
    if (tid < ITILE * TT / 4) {
        const int row = tid >> 7;          // 0..3
        const int col = tid & 127;         // float4 col
        ((float4*)xi_lds)[tid] = xb4[(size_t)(i0 + row) * 128 + col];
    }

    // w in registers (hot, reused every iteration).
    const float4* __restrict__ wf4 = (const float4*)w;
    const float4 w0 = wf4[lane];
    const float4 w1 = wf4[lane + 64];

    __syncthreads();

    // Wave handles j-pairs {j0, j0+1}, j0 = 2*wave + 32*s, s = 0..3.
    int j0 = 2 * wave;
    const float4* p0 = &xb4[(size_t)j0 * 128];
    const float4* p1 = &xb4[(size_t)(j0 + 1) * 128];
    float4 a0 = p0[lane], c0 = p0[lane + 64];
    float4 a1 = p1[lane], c1 = p1[lane + 64];

    const float4* __restrict__ xi4 = (const float4*)xi_lds;

    for (int s = 0; s < VV / (NWAVES * JTILE); ++s) {   // 4 iterations
        // Unconditional wrap-around prefetch of the next j-pair (always a
        // valid row; last iteration's fetch is discarded, L2-resident).
        const int jn = (j0 + NWAVES * JTILE) & (VV - 1);
        const float4* q0 = &xb4[(size_t)jn * 128];
        const float4* q1 = &xb4[(size_t)(jn + 1) * 128];
        const float4 na0 = q0[lane], nc0 = q0[lane + 64];
        const float4 na1 = q1[lane], nc1 = q1[lane + 64];

        float v[2 * ITILE];
#pragma unroll
        for (int r = 0; r < ITILE; ++r) {
            const float4 xr0 = xi4[r * 128 + lane];
            const float4 xr1 = xi4[r * 128 + 64 + lane];
            float s0 = 0.f, s1 = 0.f;
            s0 += fabsf(xr0.x - a0.x) * w0.x;
            s0 += fabsf(xr0.y - a0.y) * w0.y;
            s0 += fabsf(xr0.z - a0.z) * w0.z;
            s0 += fabsf(xr0.w - a0.w) * w0.w;
            s0 += fabsf(xr1.x - c0.x) * w1.x;
            s0 += fabsf(xr1.y - c0.y) * w1.y;
            s0 += fabsf(xr1.z - c0.z) * w1.z;
            s0 += fabsf(xr1.w - c0.w) * w1.w;
            s1 += fabsf(xr0.x - a1.x) * w0.x;
            s1 += fabsf(xr0.y - a1.y) * w0.y;
            s1 += fabsf(xr0.z - a1.z) * w0.z;
            s1 += fabsf(xr0.w - a1.w) * w0.w;
            s1 += fabsf(xr1.x - c1.x) * w1.x;
            s1 += fabsf(xr1.y - c1.y) * w1.y;
            s1 += fabsf(xr1.z - c1.z) * w1.z;
            s1 += fabsf(xr1.w - c1.w) * w1.w;
            v[2 * r]     = s0;   // result for (i0+r, j0)
            v[2 * r + 1] = s1;   // result for (i0+r, j0+1)
        }

        // Joint-8 butterfly, truncated at off=4 (depth 3, 7 shuffles).
        // Afterwards lane L holds the 8-lane-octet partial of v[L&7].
        float t0 = (lane & 1) ? v[1] : v[0], t0s = (lane & 1) ? v[0] : v[1];
        float t1 = (lane & 1) ? v[3] : v[2], t1s = (lane & 1) ? v[2] : v[3];
        float t2 = (lane & 1) ? v[5] : v[4], t2s = (lane & 1) ? v[4] : v[5];
        float t3 = (lane & 1) ? v[7] : v[6], t3s = (lane & 1) ? v[6] : v[7];
        t0 += __shfl_xor(t0s, 1, 64);
        t1 += __shfl_xor(t1s, 1, 64);
        t2 += __shfl_xor(t2s, 1, 64);
        t3 += __shfl_xor(t3s, 1, 64);
        float u0 = (lane & 2) ? t1 : t0, u0s = (lane & 2) ? t0 : t1;
        float u1 = (lane & 2) ? t3 : t2, u1s = (lane & 2) ? t2 : t3;
        u0 += __shfl_xor(u0s, 2, 64);
        u1 += __shfl_xor(u1s, 2, 64);
        float z = (lane & 4) ? u1 : u0, zs = (lane & 4) ? u0 : u1;
        z += __shfl_xor(zs, 4, 64);

        // Store octet partial: k = lane&7 -> (i_local = k>>1, j = j0 + (k&1)).
        sp[lane & 7][j0 >> 1][lane >> 3] = z;

        j0 += NWAVES * JTILE;
        a0 = na0; c0 = nc0; a1 = na1; c1 = nc1;
    }
    __syncthreads();

    // Softmax: waves 0..3, one i-row each. score(i,j) = relu(sum of 8 partials).
    if (wave < ITILE) {
        const float4* __restrict__ spf = (const float4*)sp;
        // j = lane
        int o = ((2 * wave + (lane & 1)) * 64 + (lane >> 1)) * 2;
        float4 u0 = spf[o], u1 = spf[o + 1];
        float sc0 = ((u0.x + u0.y) + (u0.z + u0.w)) + ((u1.x + u1.y) + (u1.z + u1.w));
        // j = lane + 64
        const int jj = lane + 64;
        o = ((2 * wave + (jj & 1)) * 64 + (jj >> 1)) * 2;
        u0 = spf[o]; u1 = spf[o + 1];
        float sc1 = ((u0.x + u0.y) + (u0.z + u0.w)) + ((u1.x + u1.y) + (u1.z + u1.w));

        sc0 = fmaxf(sc0, 0.f);   // ReLU after combining partials
        sc1 = fmaxf(sc1, 0.f);

        float m = fmaxf(sc0, sc1);
#pragma unroll
        for (int off = 32; off >= 1; off >>= 1)
            m = fmaxf(m, __shfl_xor(m, off, 64));
        const float e0 = __expf(sc0 - m);
        const float e1 = __expf(sc1 - m);
        float sum = e0 + e1;
#pragma unroll
        for (int off = 32; off >= 1; off >>= 1)
            sum += __shfl_xor(sum, off, 64);
        const float inv = __frcp_rn(sum);
        float* __restrict__ og = out + ((size_t)b * VV + i0 + wave) * VV;
        og[lane]      = e0 * inv;
        og[lane + 64] = e1 * inv;
    }
}

extern "C" void kernel_launch(void* const* d_in, const int* in_sizes, int n_in,
                              void* d_out, int out_size, void* d_ws, size_t ws_size,
                              hipStream_t stream) {
    const float* x = (const float*)d_in[0];   // [8,128,512] f32
    const float* w = (const float*)d_in[1];   // [512] f32
    float* out = (float*)d_out;               // [8,128,128] f32

    dim3 grid(BB * (VV / ITILE));   // 256 blocks, one per CU
    dim3 block(NWAVES * 64);        // 1024 threads = 16 waves
    hipLaunchKernelGGL(DiffGraphLearn_kernel, grid, block, 0, stream, x, w, out);
}

// Round 6
// 12.220 us; speedup vs baseline: 1.2998x; 1.0708x over previous
//
#include <hip/hip_runtime.h>
#include <hip/hip_bf16.h>

#define BB 8
#define VV 128
#define TT 512
#define ITILE 4      // i-rows per block
#define NWAVES 16    // 1024 threads per block -> 4 waves/SIMD, 1 block/CU

// One DPP reduction step: x += dpp_mov(x, CTRL). VALU pipe (no DS latency).
// bound_ctrl=true -> lanes with no valid source contribute 0.
template <int CTRL>
__device__ __forceinline__ float dppadd(float x) {
    int y = __builtin_amdgcn_update_dpp(0, __float_as_int(x), CTRL, 0xF, 0xF, true);
    return x + __int_as_float(y);
}

// Full 64-lane sum; result valid in lane 63. Six dependent VALU steps
// (~4 cyc each) instead of six dependent ds_bpermute (~30 cyc each).
__device__ __forceinline__ float wave_sum_dpp(float x) {
    x = dppadd<0xB1>(x);    // quad_perm(1,0,3,2): pair sums
    x = dppadd<0x4E>(x);    // quad_perm(2,3,0,1): quad sums
    x = dppadd<0x114>(x);   // row_shr:4
    x = dppadd<0x118>(x);   // row_shr:8 -> lanes 12..15 of each row have row sum
    x = dppadd<0x142>(x);   // row_bcast15 -> lane 31 has rows0+1, lane 63 rows2+3
    x = dppadd<0x143>(x);   // row_bcast31 -> lane 63 has all 64
    return x;
}

__global__ __launch_bounds__(1024)
void DiffGraphLearn_kernel(const float* __restrict__ x,
                           const float* __restrict__ w,
                           float* __restrict__ out) {
    const int blk  = blockIdx.x;           // b*32 + itile
    const int b    = blk >> 5;
    const int i0   = (blk & 31) * ITILE;
    const int tid  = threadIdx.x;
    const int lane = tid & 63;
    const int wave = tid >> 6;             // 0..15

    __shared__ float scores[ITILE][VV];

    const float*  __restrict__ xb  = x + (size_t)b * VV * TT;
    const float4* __restrict__ xb4 = (const float4*)xb;

    // Hoist w and the ITILE xi rows into registers (float4 index lane, lane+64).
    const float4* __restrict__ wf4 = (const float4*)w;
    const float4 w0 = wf4[lane];
    const float4 w1 = wf4[lane + 64];
    float4 xi0[ITILE], xi1[ITILE];
#pragma unroll
    for (int r = 0; r < ITILE; ++r) {
        xi0[r] = xb4[(size_t)(i0 + r) * 128 + lane];
        xi1[r] = xb4[(size_t)(i0 + r) * 128 + 64 + lane];
    }

    // j loop: wave handles j = wave + 16*s (8 iterations), software-pipelined
    // with an unconditional wrap-around prefetch (always a valid row).
    int j = wave;
    float4 a = xb4[(size_t)j * 128 + lane];
    float4 c = xb4[(size_t)j * 128 + 64 + lane];

    for (int s = 0; s < VV / NWAVES; ++s) {
        const int jn = (j + NWAVES) & (VV - 1);
        const float4 na = xb4[(size_t)jn * 128 + lane];
        const float4 nc = xb4[(size_t)jn * 128 + 64 + lane];

        float acc[ITILE];
#pragma unroll
        for (int r = 0; r < ITILE; ++r) {
            float v = 0.f;
            v += fabsf(xi0[r].x - a.x) * w0.x;
            v += fabsf(xi0[r].y - a.y) * w0.y;
            v += fabsf(xi0[r].z - a.z) * w0.z;
            v += fabsf(xi0[r].w - a.w) * w0.w;
            v += fabsf(xi1[r].x - c.x) * w1.x;
            v += fabsf(xi1[r].y - c.y) * w1.y;
            v += fabsf(xi1[r].z - c.z) * w1.z;
            v += fabsf(xi1[r].w - c.w) * w1.w;
            acc[r] = v;
        }

        // Four independent DPP reduction chains (interleave for ILP).
#pragma unroll
        for (int r = 0; r < ITILE; ++r)
            acc[r] = wave_sum_dpp(acc[r]);

        if (lane == 63) {
#pragma unroll
            for (int r = 0; r < ITILE; ++r)
                scores[r][j] = fmaxf(acc[r], 0.f);   // ReLU at store
        }

        j += NWAVES;
        a = na;
        c = nc;
    }
    __syncthreads();

    // Row softmax: waves 0..3 each handle one of the ITILE rows.
    if (wave < ITILE) {
        const float s0 = scores[wave][lane];
        const float s1 = scores[wave][lane + 64];
        float m = fmaxf(s0, s1);
#pragma unroll
        for (int off = 32; off >= 1; off >>= 1)
            m = fmaxf(m, __shfl_xor(m, off, 64));
        const float e0 = __expf(s0 - m);
        const float e1 = __expf(s1 - m);
        float sum = e0 + e1;
#pragma unroll
        for (int off = 32; off >= 1; off >>= 1)
            sum += __shfl_xor(sum, off, 64);
        const float inv = __frcp_rn(sum);
        float* __restrict__ o = out + ((size_t)b * VV + i0 + wave) * VV;
        o[lane]      = e0 * inv;
        o[lane + 64] = e1 * inv;
    }
}

extern "C" void kernel_launch(void* const* d_in, const int* in_sizes, int n_in,
                              void* d_out, int out_size, void* d_ws, size_t ws_size,
                              hipStream_t stream) {
    const float* x = (const float*)d_in[0];   // [8,128,512] f32
    const float* w = (const float*)d_in[1];   // [512] f32
    float* out = (float*)d_out;               // [8,128,128] f32

    dim3 grid(BB * (VV / ITILE));   // 256 blocks, one per CU
    dim3 block(NWAVES * 64);        // 1024 threads = 16 waves
    hipLaunchKernelGGL(DiffGraphLearn_kernel, grid, block, 0, stream, x, w, out);
}